// Round 11
// baseline (8371.428 us; speedup 1.0000x reference)
//
#include <hip/hip_runtime.h>
#include <hip/hip_bf16.h>

#define H_DIM 1024
#define B_DIM 64
#define T_DIM 512
#define I_PAD 128
#define I_ORIG 118
#define FC_DIM 16
#define HB (B_DIM * H_DIM)

typedef __hip_bfloat16 bf16;
typedef __attribute__((ext_vector_type(8))) short short8v;
typedef __attribute__((ext_vector_type(4))) float f32x4;

#define MFMA16(a, b, c) __builtin_amdgcn_mfma_f32_16x16x32_bf16(a, b, c, 0, 0, 0)

__device__ __forceinline__ short8v ldg8(const bf16* p) {
    return *reinterpret_cast<const short8v*>(p);
}
// 16B load bypassing L1/L2 (fresh from coherence point)
__device__ __forceinline__ short8v ld_byp16(const bf16* p) {
    union { unsigned long long u[2]; short8v v; } r;
    const unsigned long long* q = reinterpret_cast<const unsigned long long*>(p);
    r.u[0] = __hip_atomic_load(q,     __ATOMIC_RELAXED, __HIP_MEMORY_SCOPE_AGENT);
    r.u[1] = __hip_atomic_load(q + 1, __ATOMIC_RELAXED, __HIP_MEMORY_SCOPE_AGENT);
    return r.v;
}
__device__ __forceinline__ unsigned short f2bf_bits(float f) {
    union { bf16 h; unsigned short s; } u;
    u.h = __float2bfloat16(f);
    return u.s;
}
__device__ __forceinline__ unsigned long long ld_coh64(const unsigned long long* p) {
    return __hip_atomic_load(p, __ATOMIC_RELAXED, __HIP_MEMORY_SCOPE_AGENT);
}
__device__ __forceinline__ void st_coh(unsigned* p, unsigned v) {
    __hip_atomic_store(p, v, __ATOMIC_RELAXED, __HIP_MEMORY_SCOPE_AGENT);
}

// ---------------------------------------------------------------------------
// x[b][t][i] f32 -> x_bf[t][b][c] bf16 (c padded 118->128 with zeros)
// ---------------------------------------------------------------------------
__global__ __launch_bounds__(256) void cvt_x_kernel(
    const float* __restrict__ x, bf16* __restrict__ out)
{
    int idx  = blockIdx.x * 256 + threadIdx.x;
    int c    = idx & 127;
    int rest = idx >> 7;
    int b    = rest & 63;
    int t    = rest >> 6;
    float v  = (c < I_ORIG) ? x[((long)b * T_DIM + t) * I_ORIG + c] : 0.0f;
    out[idx] = __float2bfloat16(v);
}

__global__ __launch_bounds__(256) void cvt_pad(
    const float* __restrict__ in, bf16* __restrict__ out,
    int kin, int kp, long total)
{
    long idx = (long)blockIdx.x * 256 + threadIdx.x;
    if (idx >= total) return;
    int  c = (int)(idx % kp);
    long r = idx / kp;
    out[idx] = __float2bfloat16(c < kin ? in[r * kin + c] : 0.0f);
}

// ---------------------------------------------------------------------------
// TWO-LAYER concurrent encoder. grid 256 x 512 threads (8 waves, 1 block/CU).
// bn = bid&63 (j-tile 16), grp = bid>>6 (batch-16 rows).
// Waves: lyr = w>>2 (0: layer1, 1: layer2), wq = w&3 (k-quarter of 1024).
// Per wave per step the work is EXACTLY R7's: 8 A-frags, 24 hidden MFMAs,
// 4-wave LDS reduce, 1-element combine, sc1 store -> vmcnt(0) -> flag.
// Layer1: Whh1+Wx1 in LDS; h1 slots write-once (cached reads); x prefetch
//   post-flag; poll = own-layer flags >= t (16B via two 8B relaxed loads).
// Layer2: Whh2/Wx2 from global (XCD-L2 resident, ~1.5MB/XCD footprint).
//   Two-phase poll: (1) L1 flags >= t+1 -> ai = h1(t) cached loads + input
//   MFMAs (off the L2-recurrence chain; L1 leads in steady state);
//   (2) L2 flags >= t -> ah2 bypass loads (4-slot ring) + hidden MFMAs.
// Intra-layer reduce sync: LDS release/acquire counters (NO __syncthreads in
// the loop -- it would couple the two layers). red-buffer reuse across steps
// is safe by flag induction (write at t+1 gated on all own-layer flags>=t+1,
// set only after each wave's reduce-reads of step t).
// Bias added ONCE post-reduce (R9 lesson).
// ---------------------------------------------------------------------------
__global__ __launch_bounds__(512, 2) void gru_twolayer(
    const bf16* __restrict__ x_bf,
    const bf16* __restrict__ Wx1, const bf16* __restrict__ Wh1,
    const bf16* __restrict__ Wx2, const bf16* __restrict__ Wh2,
    const float* __restrict__ bih1, const float* __restrict__ bhh1,
    const float* __restrict__ bih2, const float* __restrict__ bhh2,
    bf16* h1all,                    // slot s = h1(s-1); read slot t, write t+1
    bf16* h2rg,                     // ring: step t reads slot (t+3)&3, writes t&3
    float* hf1f, float* hf2f,
    unsigned* flags)                // [grp][bn][lyr][wq] dwords
{
    extern __shared__ char smem[];
    constexpr int WH = 3 * 16 * 1024 * 2;     // 98304 (Whh1, swizzled)
    constexpr int WX = 3 * 16 * 128 * 2;      // 12288 (Wx1)
    float* red1 = (float*)(smem + WH + WX);   // 4608 floats
    float* red2 = red1 + 4608;                // 4608 floats
    unsigned* cntb = (unsigned*)(red2 + 4608);// 8 dwords

    const int tid  = threadIdx.x;
    const int w    = tid >> 6;
    const int lane = tid & 63;
    const int ln   = lane & 15;
    const int lk   = lane >> 4;
    const int lyr  = w >> 2;
    const int wq   = w & 3;
    const int bid  = blockIdx.x;
    const int bn   = bid & 63;
    const int grp  = bid >> 6;
    const int j0   = bn << 4;
    const int m0   = grp << 4;
    const int j    = j0 + ln;

    // ---- stage Whh1 (swizzled 2048B rows) + Wx1 (256B rows)
    for (int c = tid; c < WH / 16; c += 512) {
        int lin = c * 16;
        int row = lin >> 11;
        int wb  = lin & 2047;
        int g   = row >> 4, jj = row & 15;
        const bf16* src = Wh1 + ((long)(g * 1024 + j0 + jj) << 10) + (wb >> 1);
        *reinterpret_cast<short8v*>(smem + (lin ^ ((jj & 7) << 4))) = ldg8(src);
    }
    for (int c = tid; c < WX / 16; c += 512) {
        int lin = c * 16;
        int row = lin >> 8;
        int wb  = lin & 255;
        int g   = row >> 4, jj = row & 15;
        const bf16* src = Wx1 + (long)(g * 1024 + j0 + jj) * I_PAD + (wb >> 1);
        *reinterpret_cast<short8v*>(smem + WH + (lin ^ ((jj & 7) << 4))) = ldg8(src);
    }
    if (tid < 8) cntb[tid] = 0;
    __syncthreads();          // one-time only

    const float* bihv = lyr ? bih2 : bih1;
    const float* bhhv = lyr ? bhh2 : bhh1;
    const float b_r  = bihv[j] + bhhv[j];
    const float b_z  = bihv[j + 1024] + bhhv[j + 1024];
    const float b_ni = bihv[j + 2048];
    const float b_nh = bhhv[j + 2048];

    const int wko  = wq << 8;
    const int wkox = wq << 5;
    const int swz  = (ln & 7) << 4;
    const int whb0 = ln * 2048 + ((wko + lk * 8) << 1);
    const int crow = (wq << 2) | lk;
    const int gm   = m0 + crow;
    const long opos = (long)gm * H_DIM + j;

    unsigned* myflag = flags + (grp << 9) + (bn << 3) + (lyr << 2) + wq;
    const unsigned long long* pl =
        (const unsigned long long*)(flags + (grp << 9) + (lane << 3));
    // pl[0..1] = L1 flags (4 dwords), pl[2..3] = L2 flags

    float* red = lyr ? red2 : red1;
    unsigned* cnt = cntb + (lyr << 2);
    float hprev = 0.0f;

    if (lyr == 0) {
        // =========================== LAYER 1 ===========================
        short8v xcur;
        {
            const bf16* xr = x_bf + (long)(m0 + ln) * I_PAD + wkox + lk * 8;
            xcur = ldg8(xr);
        }
        for (int t = 0; t < T_DIM; ++t) {
            f32x4 aR{0,0,0,0}, aZ{0,0,0,0}, aNI{0,0,0,0}, aNH{0,0,0,0};

            // x-side gates (pre-poll; LDS Wx1)
            {
                int o = WH + ln * 256 + ((wkox + lk * 8) << 1);
                short8v br  = *(const short8v*)(smem + ((o       ) ^ swz));
                short8v bz  = *(const short8v*)(smem + ((o + 4096) ^ swz));
                short8v bnn = *(const short8v*)(smem + ((o + 8192) ^ swz));
                aR  = MFMA16(xcur, br,  aR);
                aZ  = MFMA16(xcur, bz,  aZ);
                aNI = MFMA16(xcur, bnn, aNI);
            }

            // poll own-layer flags >= t (bare spin)
            if (t > 0) {
                const unsigned tgt = (unsigned)t;
                while (true) {
                    unsigned long long q0 = ld_coh64(pl), q1 = ld_coh64(pl + 1);
                    int ok = ((unsigned)q0 >= tgt) & ((unsigned)(q0 >> 32) >= tgt)
                           & ((unsigned)q1 >= tgt) & ((unsigned)(q1 >> 32) >= tgt);
                    if (__all(ok)) break;
                }
                asm volatile("" ::: "memory");
            }

            // hidden A (cached; write-once slot t) + MFMAs (LDS Whh1)
            const bf16* ha = h1all + (long)t * HB + (long)(m0 + ln) * H_DIM
                             + wko + lk * 8;
            short8v ah[8];
#pragma unroll
            for (int ks = 0; ks < 8; ++ks) ah[ks] = ldg8(ha + ks * 32);
#pragma unroll
            for (int ks = 0; ks < 8; ++ks) {
                int o = whb0 + ks * 64;
                short8v br  = *(const short8v*)(smem + ((o        ) ^ swz));
                short8v bz  = *(const short8v*)(smem + ((o + 32768) ^ swz));
                short8v bnn = *(const short8v*)(smem + ((o + 65536) ^ swz));
                aR  = MFMA16(ah[ks], br,  aR);
                aZ  = MFMA16(ah[ks], bz,  aZ);
                aNH = MFMA16(ah[ks], bnn, aNH);
            }

            // partials + intra-layer 4-wave LDS sync
#pragma unroll
            for (int a = 0; a < 4; ++a) {
                f32x4 v = (a == 0) ? aR : (a == 1) ? aZ : (a == 2) ? aNI : aNH;
                int base = ((wq << 2) + a) * 288 + (lk * 4) * 18 + ln;
#pragma unroll
                for (int e = 0; e < 4; ++e) red[base + e * 18] = v[e];
            }
            const unsigned st = (unsigned)(t + 1);
            __hip_atomic_store(cnt + wq, st, __ATOMIC_RELEASE,
                               __HIP_MEMORY_SCOPE_WORKGROUP);
            while (__hip_atomic_load(cnt + 0, __ATOMIC_ACQUIRE, __HIP_MEMORY_SCOPE_WORKGROUP) < st ||
                   __hip_atomic_load(cnt + 1, __ATOMIC_ACQUIRE, __HIP_MEMORY_SCOPE_WORKGROUP) < st ||
                   __hip_atomic_load(cnt + 2, __ATOMIC_ACQUIRE, __HIP_MEMORY_SCOPE_WORKGROUP) < st ||
                   __hip_atomic_load(cnt + 3, __ATOMIC_ACQUIRE, __HIP_MEMORY_SCOPE_WORKGROUP) < st) {}

            float sR = 0, sZ = 0, sNI = 0, sNH = 0;
#pragma unroll
            for (int w2 = 0; w2 < 4; ++w2) {
                int tb = (w2 << 2) * 288 + crow * 18 + ln;
                sR  += red[tb];
                sZ  += red[tb + 288];
                sNI += red[tb + 576];
                sNH += red[tb + 864];
            }
            float rr = 1.0f / (1.0f + __expf(-(sR + b_r)));
            float zz = 1.0f / (1.0f + __expf(-(sZ + b_z)));
            float xn = (sNI + b_ni) + rr * (sNH + b_nh);
            float nn = 2.0f / (1.0f + __expf(-2.0f * xn)) - 1.0f;
            float hv = (1.0f - zz) * nn + zz * hprev;
            hprev = hv;

            bf16* dst = h1all + (long)(t + 1) * HB;
            float ho = __shfl_xor(hv, 1);
            if ((ln & 1) == 0) {
                unsigned pk = (unsigned)f2bf_bits(hv)
                            | ((unsigned)f2bf_bits(ho) << 16);
                st_coh((unsigned*)(dst + (opos & ~1L)), pk);
            }
            if (t == T_DIM - 1) hf1f[opos] = hv;

            asm volatile("s_waitcnt vmcnt(0)" ::: "memory");
            if (lane == 0) st_coh(myflag, st);      // always (L2 needs t=511)

            if (t + 1 < T_DIM) {
                const bf16* xr = x_bf + (long)(t + 1) * (B_DIM * I_PAD)
                               + (long)(m0 + ln) * I_PAD + wkox + lk * 8;
                xcur = ldg8(xr);
            }
        }
    } else {
        // =========================== LAYER 2 ===========================
        const bf16* wx2r = Wx2 + (long)j * 1024 + wko + lk * 8;
        const bf16* wh2r = Wh2 + (long)j * 1024 + wko + lk * 8;
        for (int t = 0; t < T_DIM; ++t) {
            // phase 1: L1 flags >= t+1 (h1(t) ready; steady-state instant)
            {
                const unsigned tgt = (unsigned)(t + 1);
                while (true) {
                    unsigned long long q0 = ld_coh64(pl), q1 = ld_coh64(pl + 1);
                    int ok = ((unsigned)q0 >= tgt) & ((unsigned)(q0 >> 32) >= tgt)
                           & ((unsigned)q1 >= tgt) & ((unsigned)(q1 >> 32) >= tgt);
                    if (__all(ok)) break;
                }
                asm volatile("" ::: "memory");
            }
            // input side: ai = h1(t) (cached, write-once) x Wx2 (global)
            const bf16* xa = h1all + (long)(t + 1) * HB + (long)(m0 + ln) * H_DIM
                             + wko + lk * 8;
            short8v ai[8];
#pragma unroll
            for (int ks = 0; ks < 8; ++ks) ai[ks] = ldg8(xa + ks * 32);

            f32x4 aR{0,0,0,0}, aZ{0,0,0,0}, aNI{0,0,0,0}, aNH{0,0,0,0};
#pragma unroll
            for (int ks = 0; ks < 8; ++ks) {
                short8v br  = ldg8(wx2r + ks * 32);
                short8v bz  = ldg8(wx2r + (1 << 20) + ks * 32);
                short8v bnn = ldg8(wx2r + (2 << 20) + ks * 32);
                aR  = MFMA16(ai[ks], br,  aR);
                aZ  = MFMA16(ai[ks], bz,  aZ);
                aNI = MFMA16(ai[ks], bnn, aNI);
            }

            // phase 2: L2 flags >= t (h2(t-1) ready)
            if (t > 0) {
                const unsigned tgt = (unsigned)t;
                while (true) {
                    unsigned long long q2 = ld_coh64(pl + 2), q3 = ld_coh64(pl + 3);
                    int ok = ((unsigned)q2 >= tgt) & ((unsigned)(q2 >> 32) >= tgt)
                           & ((unsigned)q3 >= tgt) & ((unsigned)(q3 >> 32) >= tgt);
                    if (__all(ok)) break;
                }
                asm volatile("" ::: "memory");
            }
            const bf16* hb = h2rg + (long)((t + 3) & 3) * HB
                             + (long)(m0 + ln) * H_DIM + wko + lk * 8;
            short8v ah[8];
#pragma unroll
            for (int ks = 0; ks < 8; ++ks) ah[ks] = ld_byp16(hb + ks * 32);
#pragma unroll
            for (int ks = 0; ks < 8; ++ks) {
                short8v br  = ldg8(wh2r + ks * 32);
                short8v bz  = ldg8(wh2r + (1 << 20) + ks * 32);
                short8v bnn = ldg8(wh2r + (2 << 20) + ks * 32);
                aR  = MFMA16(ah[ks], br,  aR);
                aZ  = MFMA16(ah[ks], bz,  aZ);
                aNH = MFMA16(ah[ks], bnn, aNH);
            }

            // partials + intra-layer 4-wave LDS sync
#pragma unroll
            for (int a = 0; a < 4; ++a) {
                f32x4 v = (a == 0) ? aR : (a == 1) ? aZ : (a == 2) ? aNI : aNH;
                int base = ((wq << 2) + a) * 288 + (lk * 4) * 18 + ln;
#pragma unroll
                for (int e = 0; e < 4; ++e) red[base + e * 18] = v[e];
            }
            const unsigned st = (unsigned)(t + 1);
            __hip_atomic_store(cnt + wq, st, __ATOMIC_RELEASE,
                               __HIP_MEMORY_SCOPE_WORKGROUP);
            while (__hip_atomic_load(cnt + 0, __ATOMIC_ACQUIRE, __HIP_MEMORY_SCOPE_WORKGROUP) < st ||
                   __hip_atomic_load(cnt + 1, __ATOMIC_ACQUIRE, __HIP_MEMORY_SCOPE_WORKGROUP) < st ||
                   __hip_atomic_load(cnt + 2, __ATOMIC_ACQUIRE, __HIP_MEMORY_SCOPE_WORKGROUP) < st ||
                   __hip_atomic_load(cnt + 3, __ATOMIC_ACQUIRE, __HIP_MEMORY_SCOPE_WORKGROUP) < st) {}

            float sR = 0, sZ = 0, sNI = 0, sNH = 0;
#pragma unroll
            for (int w2 = 0; w2 < 4; ++w2) {
                int tb = (w2 << 2) * 288 + crow * 18 + ln;
                sR  += red[tb];
                sZ  += red[tb + 288];
                sNI += red[tb + 576];
                sNH += red[tb + 864];
            }
            float rr = 1.0f / (1.0f + __expf(-(sR + b_r)));
            float zz = 1.0f / (1.0f + __expf(-(sZ + b_z)));
            float xn = (sNI + b_ni) + rr * (sNH + b_nh);
            float nn = 2.0f / (1.0f + __expf(-2.0f * xn)) - 1.0f;
            float hv = (1.0f - zz) * nn + zz * hprev;
            hprev = hv;

            bf16* dst = h2rg + (long)(t & 3) * HB;
            float ho = __shfl_xor(hv, 1);
            if ((ln & 1) == 0) {
                unsigned pk = (unsigned)f2bf_bits(hv)
                            | ((unsigned)f2bf_bits(ho) << 16);
                st_coh((unsigned*)(dst + (opos & ~1L)), pk);
            }
            if (t == T_DIM - 1) hf2f[opos] = hv;

            asm volatile("s_waitcnt vmcnt(0)" ::: "memory");
            if (lane == 0) st_coh(myflag, st);
        }
    }
}

// ---------------------------------------------------------------------------
// Single-step GRU cell (decoder) — R7 kernel.
// ---------------------------------------------------------------------------
template<int WXK, bool WXG, bool SEQ>
__global__ __launch_bounds__(256, 1) void gru_pass(
    const bf16* __restrict__ xbase, long xstride,
    const bf16* __restrict__ WxG,
    const bf16* __restrict__ WhG,
    const float* __restrict__ bih, const float* __restrict__ bhh,
    const bf16* hin, bf16* hout,
    const float* f_init, float* f_final,
    int nsteps, unsigned* flags)
{
    extern __shared__ char smem[];
    constexpr int WH_BYTES = 3 * 16 * 1024 * 2;
    constexpr int WX_BYTES = WXG ? 0 : 3 * 16 * WXK * 2;
    float* sm_red = (float*)(smem + WH_BYTES + WX_BYTES);

    const int tid  = threadIdx.x;
    const int w    = tid >> 6;
    const int lane = tid & 63;
    const int ln   = lane & 15;
    const int lk   = lane >> 4;
    const int bid  = blockIdx.x;
    const int bn   = bid & 63;
    const int grp  = bid >> 6;
    const int j0   = bn * 16;
    const int m0   = grp * 16;
    const int j    = j0 + ln;

    for (int c = tid; c < WH_BYTES / 16; c += 256) {
        int lin = c * 16;
        int row = lin >> 11;
        int wb  = lin & 2047;
        int g   = row >> 4, jj = row & 15;
        const bf16* src = WhG + ((long)(g * 1024 + j0 + jj) << 10) + (wb >> 1);
        *reinterpret_cast<short8v*>(smem + (lin ^ ((jj & 7) << 4))) = ldg8(src);
    }
    if constexpr (!WXG) {
        for (int c = tid; c < WX_BYTES / 16; c += 256) {
            int lin = c * 16;
            int row = lin / (WXK * 2);
            int wb  = lin % (WXK * 2);
            int g   = row >> 4, jj = row & 15;
            const bf16* src = WxG + (long)(g * 1024 + j0 + jj) * WXK + (wb >> 1);
            *reinterpret_cast<short8v*>(smem + WH_BYTES + (lin ^ ((jj & 7) << 4))) = ldg8(src);
        }
    }
    __syncthreads();

    const int wkoh = w << 8;
    const int wkox = (WXK == 128) ? (w << 5) : (w << 8);
    const int swz  = (ln & 7) << 4;
    const int whb0 = ln * 2048 + ((wkoh + lk * 8) << 1);

    const float bias_r  = bih[j] + bhh[j];
    const float bias_z  = bih[j + H_DIM] + bhh[j + H_DIM];
    const float bias_ni = bih[j + 2 * H_DIM];
    const float bias_nh = bhh[j + 2 * H_DIM];

    const int  crow = (w << 2) | lk;
    const int  gm   = m0 + crow;
    const long opos = (long)gm * H_DIM + j;

    float hprev = f_init ? f_init[opos] : 0.0f;

    constexpr int NKX = (WXK == 128) ? 1 : 8;
    short8v xcur[NKX];
    {
        const bf16* xr = xbase + (long)(m0 + ln) * WXK + wkox + lk * 8;
#pragma unroll
        for (int ks = 0; ks < NKX; ++ks) xcur[ks] = ldg8(xr + ks * 32);
    }

    for (int t = 0; t < nsteps; ++t) {
        f32x4 aR{0,0,0,0}, aZ{0,0,0,0}, aNI{0,0,0,0}, aNH{0,0,0,0};

        if constexpr (WXK == 128) {
            int o = WH_BYTES + ln * 256 + ((wkox + lk * 8) << 1);
            short8v br  = *(const short8v*)(smem + ((o       ) ^ swz));
            short8v bz  = *(const short8v*)(smem + ((o + 4096) ^ swz));
            short8v bnn = *(const short8v*)(smem + ((o + 8192) ^ swz));
            aR  = MFMA16(xcur[0], br,  aR);
            aZ  = MFMA16(xcur[0], bz,  aZ);
            aNI = MFMA16(xcur[0], bnn, aNI);
        } else {
            const bf16* wxr = WxG + (long)(j0 + ln) * 1024 + wkox + lk * 8;
#pragma unroll
            for (int ks = 0; ks < 8; ++ks) {
                short8v br  = ldg8(wxr + ks * 32);
                short8v bz  = ldg8(wxr + (1 << 20) + ks * 32);
                short8v bnn = ldg8(wxr + (2 << 20) + ks * 32);
                aR  = MFMA16(xcur[ks], br,  aR);
                aZ  = MFMA16(xcur[ks], bz,  aZ);
                aNI = MFMA16(xcur[ks], bnn, aNI);
            }
        }

        const bf16* bf_in = SEQ ? hin + (long)t * HB : hin + (long)(t & 1) * HB;
        const bf16* ha = bf_in + (long)(m0 + ln) * H_DIM + wkoh + lk * 8;
        short8v ah[8];
#pragma unroll
        for (int ks = 0; ks < 8; ++ks)
            ah[ks] = SEQ ? ldg8(ha + ks * 32) : ld_byp16(ha + ks * 32);

#pragma unroll
        for (int ks = 0; ks < 8; ++ks) {
            int o = whb0 + ks * 64;
            short8v br  = *(const short8v*)(smem + ((o        ) ^ swz));
            short8v bz  = *(const short8v*)(smem + ((o + 32768) ^ swz));
            short8v bnn = *(const short8v*)(smem + ((o + 65536) ^ swz));
            aR  = MFMA16(ah[ks], br,  aR);
            aZ  = MFMA16(ah[ks], bz,  aZ);
            aNH = MFMA16(ah[ks], bnn, aNH);
        }

        float* red = sm_red + (t & 1) * 4608;
#pragma unroll
        for (int a = 0; a < 4; ++a) {
            f32x4 v = (a == 0) ? aR : (a == 1) ? aZ : (a == 2) ? aNI : aNH;
            int base = ((w << 2) + a) * 288 + (lk * 4) * 18 + ln;
#pragma unroll
            for (int e = 0; e < 4; ++e)
                red[base + e * 18] = v[e];
        }
        __syncthreads();

        float sR = 0, sZ = 0, sNI = 0, sNH = 0;
#pragma unroll
        for (int w2 = 0; w2 < 4; ++w2) {
            int tb = (w2 << 2) * 288 + crow * 18 + ln;
            sR  += red[tb];
            sZ  += red[tb + 288];
            sNI += red[tb + 576];
            sNH += red[tb + 864];
        }
        float rr = 1.0f / (1.0f + __expf(-(sR + bias_r)));
        float zz = 1.0f / (1.0f + __expf(-(sZ + bias_z)));
        float xn = (sNI + bias_ni) + rr * (sNH + bias_nh);
        float nn = 2.0f / (1.0f + __expf(-2.0f * xn)) - 1.0f;
        float hv = (1.0f - zz) * nn + zz * hprev;
        hprev = hv;

        {
            bf16* wr = SEQ ? hout + (long)t * HB
                           : const_cast<bf16*>(hin) + (long)((t + 1) & 1) * HB;
            float ho = __shfl_xor(hv, 1);
            if ((ln & 1) == 0) {
                unsigned pk = (unsigned)f2bf_bits(hv)
                            | ((unsigned)f2bf_bits(ho) << 16);
                st_coh((unsigned*)(wr + (opos & ~1L)), pk);
            }
        }
        if (t == nsteps - 1 && f_final) f_final[opos] = hv;
        (void)flags;
    }
}

// ---------------------------------------------------------------------------
__global__ __launch_bounds__(1024) void head_kernel(
    const float* __restrict__ h2,
    const float* __restrict__ fc_W, const float* __restrict__ fc_b,
    const float* __restrict__ out_W, const float* __restrict__ out_b,
    float* __restrict__ y)
{
    __shared__ float acc_s[FC_DIM][B_DIM];
    const int b = threadIdx.x & 63;
    const int f = threadIdx.x >> 6;
    const float* wp = fc_W + (long)f * H_DIM;
    const float* hp = h2 + (long)b * H_DIM;
    float a = fc_b[f];
#pragma unroll 8
    for (int k = 0; k < H_DIM; ++k)
        a = fmaf(hp[k], wp[k], a);
    a = fmaxf(a, 0.0f);
    acc_s[f][b] = a * out_W[f];
    __syncthreads();
    if (threadIdx.x < 64) {
        float s = out_b[0];
#pragma unroll
        for (int f2 = 0; f2 < FC_DIM; ++f2) s += acc_s[f2][b];
        y[b] = s;
    }
}

// ---------------------------------------------------------------------------
extern "C" void kernel_launch(void* const* d_in, const int* in_sizes, int n_in,
                              void* d_out, int out_size, void* d_ws, size_t ws_size,
                              hipStream_t stream)
{
    const float* x      = (const float*)d_in[0];
    const float* e_Wih0 = (const float*)d_in[1];
    const float* e_Whh0 = (const float*)d_in[2];
    const float* e_bih0 = (const float*)d_in[3];
    const float* e_bhh0 = (const float*)d_in[4];
    const float* e_Wih1 = (const float*)d_in[5];
    const float* e_Whh1 = (const float*)d_in[6];
    const float* e_bih1 = (const float*)d_in[7];
    const float* e_bhh1 = (const float*)d_in[8];
    const float* d_Wih0 = (const float*)d_in[9];
    const float* d_Whh0 = (const float*)d_in[10];
    const float* d_bih0 = (const float*)d_in[11];
    const float* d_bhh0 = (const float*)d_in[12];
    const float* d_Wih1 = (const float*)d_in[13];
    const float* d_Whh1 = (const float*)d_in[14];
    const float* d_bih1 = (const float*)d_in[15];
    const float* d_bhh1 = (const float*)d_in[16];
    const float* fc_W   = (const float*)d_in[17];
    const float* fc_b   = (const float*)d_in[18];
    const float* out_W  = (const float*)d_in[19];
    const float* out_b  = (const float*)d_in[20];
    (void)in_sizes; (void)n_in; (void)out_size; (void)ws_size;

    char* p = (char*)d_ws;
    auto alloc = [&](size_t bytes) -> char* {
        char* r = p; p += (bytes + 255) & ~(size_t)255; return r;
    };
    bf16*  x_bf  = (bf16*)alloc((size_t)T_DIM * B_DIM * I_PAD * 2);
    bf16*  wih0e = (bf16*)alloc(3072ull * 128 * 2);
    bf16*  whh0e = (bf16*)alloc(3072ull * 1024 * 2);
    bf16*  wih1e = (bf16*)alloc(3072ull * 1024 * 2);
    bf16*  whh1e = (bf16*)alloc(3072ull * 1024 * 2);
    bf16*  wih0d = (bf16*)alloc(3072ull * 128 * 2);
    bf16*  whh0d = (bf16*)alloc(3072ull * 1024 * 2);
    bf16*  wih1d = (bf16*)alloc(3072ull * 1024 * 2);
    bf16*  whh1d = (bf16*)alloc(3072ull * 1024 * 2);
    bf16*  h1all = (bf16*)alloc(514ull * HB * 2);   // slots 0..513
    bf16*  h2rg  = (bf16*)alloc(5ull * HB * 2);     // 4-slot ring + 1 spare
    bf16*  hd1b  = (bf16*)alloc((size_t)HB * 2);
    float* hf1f  = (float*)alloc((size_t)HB * 4);
    float* hf2f  = (float*)alloc((size_t)HB * 4);
    float* hd1f  = (float*)alloc((size_t)HB * 4);
    float* hd2f  = (float*)alloc((size_t)HB * 4);
    unsigned* fl = (unsigned*)alloc(8192);          // 4 grp x 64 bn x 2 lyr x 4 wq

    constexpr int RED = 2 * 4608 * 4;               // 36864
    constexpr int ST  = 98304 + 12288 + RED + 256;  // twolayer: 147712
    constexpr int S1  = 98304 + 12288 + RED;        // decoder cell 1
    constexpr int S2  = 98304 + RED;                // decoder cell 2
    (void)hipFuncSetAttribute((const void*)gru_twolayer,
                              hipFuncAttributeMaxDynamicSharedMemorySize, ST);
    (void)hipFuncSetAttribute((const void*)gru_pass<128, false, true>,
                              hipFuncAttributeMaxDynamicSharedMemorySize, S1);
    (void)hipFuncSetAttribute((const void*)gru_pass<1024, true, false>,
                              hipFuncAttributeMaxDynamicSharedMemorySize, S2);

    cvt_x_kernel<<<(T_DIM * B_DIM * I_PAD) / 256, 256, 0, stream>>>(x, x_bf);
    auto cvt = [&](const float* in, bf16* out, int kin, int kp) {
        long total = 3072L * kp;
        cvt_pad<<<(int)((total + 255) / 256), 256, 0, stream>>>(in, out, kin, kp, total);
    };
    cvt(e_Wih0, wih0e, 118, 128);
    cvt(e_Whh0, whh0e, 1024, 1024);
    cvt(e_Wih1, wih1e, 1024, 1024);
    cvt(e_Whh1, whh1e, 1024, 1024);
    cvt(d_Wih0, wih0d, 118, 128);
    cvt(d_Whh0, whh0d, 1024, 1024);
    cvt(d_Wih1, wih1d, 1024, 1024);
    cvt(d_Whh1, whh1d, 1024, 1024);

    // deterministic per-launch state
    hipMemsetAsync(h1all, 0, (size_t)HB * 2, stream);            // h1(-1) = 0
    hipMemsetAsync(h2rg + 3ull * HB, 0, (size_t)HB * 2, stream); // h2(-1) = 0 (slot 3)
    hipMemsetAsync(fl,    0, 8192, stream);

    // concurrent two-layer encoder (512 threads: waves 0-3 L1, 4-7 L2)
    gru_twolayer<<<256, 512, ST, stream>>>(
        x_bf, wih0e, whh0e, wih1e, whh1e,
        e_bih0, e_bhh0, e_bih1, e_bhh1,
        h1all, h2rg, hf1f, hf2f, fl);
    // h1(511) -> h1all slot 512 (+ hf1f); h2(511) -> ring slot 511&3 = 3 (+ hf2f)

    // decoder cell 1: x = x[:,511,:], h = h1(511) (cached write-once slot)
    gru_pass<128, false, true><<<256, 256, S1, stream>>>(
        x_bf + 511L * B_DIM * I_PAD, 0, wih0d, whh0d, d_bih0, d_bhh0,
        h1all + 512L * HB, hd1b, hf1f, hd1f, 1, nullptr);

    // decoder cell 2: x = hd1, h = h2(511) (ring slot 3; bypass reads;
    // its dummy bf16 out goes to ring slot 4 = spare)
    gru_pass<1024, true, false><<<256, 256, S2, stream>>>(
        hd1b, 0, wih1d, whh1d, d_bih1, d_bhh1,
        h2rg + 3L * HB, nullptr, hf2f, hd2f, 1, nullptr);

    head_kernel<<<1, 1024, 0, stream>>>(hd2f, fc_W, fc_b, out_W, out_b,
                                        (float*)d_out);
}

// Round 12
// 5056.447 us; speedup vs baseline: 1.6556x; 1.6556x over previous
//
#include <hip/hip_runtime.h>
#include <hip/hip_bf16.h>

#define H_DIM 1024
#define B_DIM 64
#define T_DIM 512
#define I_PAD 128
#define I_ORIG 118
#define FC_DIM 16
#define HB (B_DIM * H_DIM)

typedef __hip_bfloat16 bf16;
typedef __attribute__((ext_vector_type(8))) short short8v;
typedef __attribute__((ext_vector_type(4))) float f32x4;

#define MFMA16(a, b, c) __builtin_amdgcn_mfma_f32_16x16x32_bf16(a, b, c, 0, 0, 0)

__device__ __forceinline__ short8v ldg8(const bf16* p) {
    return *reinterpret_cast<const short8v*>(p);
}
// 16B load bypassing L1/L2 (fresh from coherence point)
__device__ __forceinline__ short8v ld_byp16(const bf16* p) {
    union { unsigned long long u[2]; short8v v; } r;
    const unsigned long long* q = reinterpret_cast<const unsigned long long*>(p);
    r.u[0] = __hip_atomic_load(q,     __ATOMIC_RELAXED, __HIP_MEMORY_SCOPE_AGENT);
    r.u[1] = __hip_atomic_load(q + 1, __ATOMIC_RELAXED, __HIP_MEMORY_SCOPE_AGENT);
    return r.v;
}
__device__ __forceinline__ unsigned short f2bf_bits(float f) {
    union { bf16 h; unsigned short s; } u;
    u.h = __float2bfloat16(f);
    return u.s;
}
__device__ __forceinline__ unsigned ld_coh(const unsigned* p) {
    return __hip_atomic_load(p, __ATOMIC_RELAXED, __HIP_MEMORY_SCOPE_AGENT);
}
__device__ __forceinline__ void st_coh(unsigned* p, unsigned v) {
    __hip_atomic_store(p, v, __ATOMIC_RELAXED, __HIP_MEMORY_SCOPE_AGENT);
}

// ---------------------------------------------------------------------------
// x[b][t][i] f32 -> x_bf[t][b][c] bf16 (c padded 118->128 with zeros)
// ---------------------------------------------------------------------------
__global__ __launch_bounds__(256) void cvt_x_kernel(
    const float* __restrict__ x, bf16* __restrict__ out)
{
    int idx  = blockIdx.x * 256 + threadIdx.x;
    int c    = idx & 127;
    int rest = idx >> 7;
    int b    = rest & 63;
    int t    = rest >> 6;
    float v  = (c < I_ORIG) ? x[((long)b * T_DIM + t) * I_ORIG + c] : 0.0f;
    out[idx] = __float2bfloat16(v);
}

__global__ __launch_bounds__(256) void cvt_pad(
    const float* __restrict__ in, bf16* __restrict__ out,
    int kin, int kp, long total)
{
    long idx = (long)blockIdx.x * 256 + threadIdx.x;
    if (idx >= total) return;
    int  c = (int)(idx % kp);
    long r = idx / kp;
    out[idx] = __float2bfloat16(c < kin ? in[r * kin + c] : 0.0f);
}

// ---------------------------------------------------------------------------
// Concurrent two-layer encoder, block-level split, REGISTER-RESIDENT Whh.
// grid 512 x 256 (4 waves). bid<256: layer1 (bn=bid&63, grp=bid>>6);
// bid>=256: layer2 (same mapping of bid-256). 2 blocks/CU (LDS = reduce only).
// Per-block step = R7 verbatim; the ONLY change: hidden-side weight B-frags
// (24 x 16B/lane) are loaded into VGPRs once before the loop, so post-poll
// MFMAs touch no memory except the 8 A-fragment loads.
// Layer1: x-side MFMAs pre-poll (Wx1 frags also in regs); poll own flags
//   >= t; ah = h1all slot t (cached, write-once); store slot t+1; flag ALWAYS.
// Layer2: phase-1 poll L1 flags >= t+1 (instant: L1 free-runs ahead, no
//   backpressure) -> ai = h1 slot t+1 (cached) x Wx2 (L2-resident stream),
//   all off the recurrence chain; phase-2 poll own flags >= t -> ah bypass
//   (4-slot ring) -> 24 register-weight MFMAs -> reduce -> combine -> store.
// Flags: fl[0..1023] = L1 (grp<<8|bn<<2|w), fl[1024..2047] = L2.
// ---------------------------------------------------------------------------
__global__ __launch_bounds__(256, 2) void gru_enc2(
    const bf16* __restrict__ x_bf,
    const bf16* __restrict__ Wx1, const bf16* __restrict__ Wh1,
    const bf16* __restrict__ Wx2, const bf16* __restrict__ Wh2,
    const float* __restrict__ bih1, const float* __restrict__ bhh1,
    const float* __restrict__ bih2, const float* __restrict__ bhh2,
    bf16* h1all,                    // slot s = h1(s-1); read t, write t+1
    bf16* h2rg,                     // ring: step t reads (t+3)&3, writes t&3
    float* hf1f, float* hf2f,
    unsigned* fl)
{
    __shared__ float sm_red[2 * 4608];

    const int tid  = threadIdx.x;
    const int w    = tid >> 6;
    const int lane = tid & 63;
    const int ln   = lane & 15;
    const int lk   = lane >> 4;
    const int bid  = blockIdx.x;
    const int lyr  = bid >> 8;
    const int b2   = bid & 255;
    const int bn   = b2 & 63;
    const int grp  = b2 >> 6;
    const int j0   = bn << 4;
    const int m0   = grp << 4;
    const int j    = j0 + ln;

    const int wko  = w << 8;                  // hidden k-quarter base
    const int crow = (w << 2) | lk;
    const int gm   = m0 + crow;
    const long opos = (long)gm * H_DIM + j;

    // ---- hidden-side weight fragments -> registers (once)
    const bf16* WhG = lyr ? Wh2 : Wh1;
    short8v whr[8], whz[8], whn[8];
    {
        const bf16* bp = WhG + (long)j * 1024 + wko + lk * 8;
#pragma unroll
        for (int ks = 0; ks < 8; ++ks) {
            whr[ks] = ldg8(bp + ks * 32);
            whz[ks] = ldg8(bp + (1 << 20) + ks * 32);
            whn[ks] = ldg8(bp + (2 << 20) + ks * 32);
        }
    }
    // layer-1 x-side fragments (K=128, quarter = 32)
    short8v wx_r{}, wx_z{}, wx_n{};
    if (lyr == 0) {
        const bf16* bx = Wx1 + (long)j * I_PAD + (w << 5) + lk * 8;
        wx_r = ldg8(bx);
        wx_z = ldg8(bx + (1 << 17));
        wx_n = ldg8(bx + (2 << 17));
    }

    const float* bihv = lyr ? bih2 : bih1;
    const float* bhhv = lyr ? bhh2 : bhh1;
    const float b_r  = bihv[j] + bhhv[j];
    const float b_z  = bihv[j + 1024] + bhhv[j + 1024];
    const float b_ni = bihv[j + 2048];
    const float b_nh = bhhv[j + 2048];

    unsigned* flbase = fl + (lyr << 10);
    unsigned* myflag = flbase + (grp << 8) + (bn << 2) + w;
    const unsigned* pollp  = flbase + (grp << 8) + (w << 6) + lane;   // own layer
    const unsigned* pollp1 = fl + (grp << 8) + (w << 6) + lane;       // L1 flags

    float hprev = 0.0f;

    if (lyr == 0) {
        // =========================== LAYER 1 ===========================
        short8v xcur;
        {
            const bf16* xr = x_bf + (long)(m0 + ln) * I_PAD + (w << 5) + lk * 8;
            xcur = ldg8(xr);
        }
        for (int t = 0; t < T_DIM; ++t) {
            f32x4 aR{0,0,0,0}, aZ{0,0,0,0}, aNI{0,0,0,0}, aNH{0,0,0,0};

            // x-side gates (pre-poll; register weights)
            aR  = MFMA16(xcur, wx_r, aR);
            aZ  = MFMA16(xcur, wx_z, aZ);
            aNI = MFMA16(xcur, wx_n, aNI);

            // poll own flags >= t (bare spin)
            if (t > 0) {
                const unsigned tgt = (unsigned)t;
                while (true) {
                    unsigned fv = ld_coh(pollp);
                    if (__all((int)(fv >= tgt))) break;
                }
                asm volatile("" ::: "memory");
            }

            // hidden A (cached; write-once slot t) + register-weight MFMAs
            const bf16* ha = h1all + (long)t * HB + (long)(m0 + ln) * H_DIM
                             + wko + lk * 8;
            short8v ah[8];
#pragma unroll
            for (int ks = 0; ks < 8; ++ks) ah[ks] = ldg8(ha + ks * 32);
#pragma unroll
            for (int ks = 0; ks < 8; ++ks) {
                aR  = MFMA16(ah[ks], whr[ks], aR);
                aZ  = MFMA16(ah[ks], whz[ks], aZ);
                aNH = MFMA16(ah[ks], whn[ks], aNH);
            }

            // K-split reduce (18-padded rows, dbuf, one sync)
            float* red = sm_red + (t & 1) * 4608;
#pragma unroll
            for (int a = 0; a < 4; ++a) {
                f32x4 v = (a == 0) ? aR : (a == 1) ? aZ : (a == 2) ? aNI : aNH;
                int base = ((w << 2) + a) * 288 + (lk * 4) * 18 + ln;
#pragma unroll
                for (int e = 0; e < 4; ++e) red[base + e * 18] = v[e];
            }
            __syncthreads();

            float sR = 0, sZ = 0, sNI = 0, sNH = 0;
#pragma unroll
            for (int w2 = 0; w2 < 4; ++w2) {
                int tb = (w2 << 2) * 288 + crow * 18 + ln;
                sR  += red[tb];
                sZ  += red[tb + 288];
                sNI += red[tb + 576];
                sNH += red[tb + 864];
            }
            float rr = 1.0f / (1.0f + __expf(-(sR + b_r)));
            float zz = 1.0f / (1.0f + __expf(-(sZ + b_z)));
            float xn = (sNI + b_ni) + rr * (sNH + b_nh);
            float nn = 2.0f / (1.0f + __expf(-2.0f * xn)) - 1.0f;
            float hv = (1.0f - zz) * nn + zz * hprev;
            hprev = hv;

            bf16* dst = h1all + (long)(t + 1) * HB;
            float ho = __shfl_xor(hv, 1);
            if ((ln & 1) == 0) {
                unsigned pk = (unsigned)f2bf_bits(hv)
                            | ((unsigned)f2bf_bits(ho) << 16);
                st_coh((unsigned*)(dst + (opos & ~1L)), pk);
            }
            if (t == T_DIM - 1) hf1f[opos] = hv;

            // ack ONLY the store, flag ALWAYS (L2 needs t=511), then prefetch
            asm volatile("s_waitcnt vmcnt(0)" ::: "memory");
            if (lane == 0) st_coh(myflag, (unsigned)(t + 1));
            if (t + 1 < T_DIM) {
                const bf16* xr = x_bf + (long)(t + 1) * (B_DIM * I_PAD)
                               + (long)(m0 + ln) * I_PAD + (w << 5) + lk * 8;
                xcur = ldg8(xr);
            }
        }
    } else {
        // =========================== LAYER 2 ===========================
        const bf16* wx2r = Wx2 + (long)j * 1024 + wko + lk * 8;
        for (int t = 0; t < T_DIM; ++t) {
            // phase 1: L1 flags >= t+1 (h1(t) ready; L1 leads -> ~instant)
            {
                const unsigned tgt = (unsigned)(t + 1);
                while (true) {
                    unsigned fv = ld_coh(pollp1);
                    if (__all((int)(fv >= tgt))) break;
                }
                asm volatile("" ::: "memory");
            }
            // input side (off recurrence chain): ai = h1(t) cached x Wx2 stream
            const bf16* xa = h1all + (long)(t + 1) * HB
                             + (long)(m0 + ln) * H_DIM + wko + lk * 8;
            short8v ai[8];
#pragma unroll
            for (int ks = 0; ks < 8; ++ks) ai[ks] = ldg8(xa + ks * 32);

            f32x4 aR{0,0,0,0}, aZ{0,0,0,0}, aNI{0,0,0,0}, aNH{0,0,0,0};
#pragma unroll
            for (int ks = 0; ks < 8; ++ks) {
                short8v br  = ldg8(wx2r + ks * 32);
                short8v bz  = ldg8(wx2r + (1 << 20) + ks * 32);
                short8v bnn = ldg8(wx2r + (2 << 20) + ks * 32);
                aR  = MFMA16(ai[ks], br,  aR);
                aZ  = MFMA16(ai[ks], bz,  aZ);
                aNI = MFMA16(ai[ks], bnn, aNI);
            }

            // phase 2: own flags >= t (recurrence gate)
            if (t > 0) {
                const unsigned tgt = (unsigned)t;
                while (true) {
                    unsigned fv = ld_coh(pollp);
                    if (__all((int)(fv >= tgt))) break;
                }
                asm volatile("" ::: "memory");
            }
            // hidden A (bypass; ring slot (t+3)&3) + REGISTER-weight MFMAs
            const bf16* hb = h2rg + (long)((t + 3) & 3) * HB
                             + (long)(m0 + ln) * H_DIM + wko + lk * 8;
            short8v ah[8];
#pragma unroll
            for (int ks = 0; ks < 8; ++ks) ah[ks] = ld_byp16(hb + ks * 32);
#pragma unroll
            for (int ks = 0; ks < 8; ++ks) {
                aR  = MFMA16(ah[ks], whr[ks], aR);
                aZ  = MFMA16(ah[ks], whz[ks], aZ);
                aNH = MFMA16(ah[ks], whn[ks], aNH);
            }

            float* red = sm_red + (t & 1) * 4608;
#pragma unroll
            for (int a = 0; a < 4; ++a) {
                f32x4 v = (a == 0) ? aR : (a == 1) ? aZ : (a == 2) ? aNI : aNH;
                int base = ((w << 2) + a) * 288 + (lk * 4) * 18 + ln;
#pragma unroll
                for (int e = 0; e < 4; ++e) red[base + e * 18] = v[e];
            }
            __syncthreads();

            float sR = 0, sZ = 0, sNI = 0, sNH = 0;
#pragma unroll
            for (int w2 = 0; w2 < 4; ++w2) {
                int tb = (w2 << 2) * 288 + crow * 18 + ln;
                sR  += red[tb];
                sZ  += red[tb + 288];
                sNI += red[tb + 576];
                sNH += red[tb + 864];
            }
            float rr = 1.0f / (1.0f + __expf(-(sR + b_r)));
            float zz = 1.0f / (1.0f + __expf(-(sZ + b_z)));
            float xn = (sNI + b_ni) + rr * (sNH + b_nh);
            float nn = 2.0f / (1.0f + __expf(-2.0f * xn)) - 1.0f;
            float hv = (1.0f - zz) * nn + zz * hprev;
            hprev = hv;

            bf16* dst = h2rg + (long)(t & 3) * HB;
            float ho = __shfl_xor(hv, 1);
            if ((ln & 1) == 0) {
                unsigned pk = (unsigned)f2bf_bits(hv)
                            | ((unsigned)f2bf_bits(ho) << 16);
                st_coh((unsigned*)(dst + (opos & ~1L)), pk);
            }
            if (t == T_DIM - 1) hf2f[opos] = hv;

            if (t + 1 < T_DIM) {
                asm volatile("s_waitcnt vmcnt(0)" ::: "memory");
                if (lane == 0) st_coh(myflag, (unsigned)(t + 1));
            }
        }
    }
}

// ---------------------------------------------------------------------------
// Single-step GRU cell (decoder) — R7 kernel.
// ---------------------------------------------------------------------------
template<int WXK, bool WXG, bool SEQ>
__global__ __launch_bounds__(256, 1) void gru_pass(
    const bf16* __restrict__ xbase, long xstride,
    const bf16* __restrict__ WxG,
    const bf16* __restrict__ WhG,
    const float* __restrict__ bih, const float* __restrict__ bhh,
    const bf16* hin, bf16* hout,
    const float* f_init, float* f_final,
    int nsteps, unsigned* flags)
{
    extern __shared__ char smem[];
    constexpr int WH_BYTES = 3 * 16 * 1024 * 2;
    constexpr int WX_BYTES = WXG ? 0 : 3 * 16 * WXK * 2;
    float* sm_red = (float*)(smem + WH_BYTES + WX_BYTES);

    const int tid  = threadIdx.x;
    const int w    = tid >> 6;
    const int lane = tid & 63;
    const int ln   = lane & 15;
    const int lk   = lane >> 4;
    const int bid  = blockIdx.x;
    const int bn   = bid & 63;
    const int grp  = bid >> 6;
    const int j0   = bn * 16;
    const int m0   = grp * 16;
    const int j    = j0 + ln;

    for (int c = tid; c < WH_BYTES / 16; c += 256) {
        int lin = c * 16;
        int row = lin >> 11;
        int wb  = lin & 2047;
        int g   = row >> 4, jj = row & 15;
        const bf16* src = WhG + ((long)(g * 1024 + j0 + jj) << 10) + (wb >> 1);
        *reinterpret_cast<short8v*>(smem + (lin ^ ((jj & 7) << 4))) = ldg8(src);
    }
    if constexpr (!WXG) {
        for (int c = tid; c < WX_BYTES / 16; c += 256) {
            int lin = c * 16;
            int row = lin / (WXK * 2);
            int wb  = lin % (WXK * 2);
            int g   = row >> 4, jj = row & 15;
            const bf16* src = WxG + (long)(g * 1024 + j0 + jj) * WXK + (wb >> 1);
            *reinterpret_cast<short8v*>(smem + WH_BYTES + (lin ^ ((jj & 7) << 4))) = ldg8(src);
        }
    }
    __syncthreads();

    const int wkoh = w << 8;
    const int wkox = (WXK == 128) ? (w << 5) : (w << 8);
    const int swz  = (ln & 7) << 4;
    const int whb0 = ln * 2048 + ((wkoh + lk * 8) << 1);

    const float bias_r  = bih[j] + bhh[j];
    const float bias_z  = bih[j + H_DIM] + bhh[j + H_DIM];
    const float bias_ni = bih[j + 2 * H_DIM];
    const float bias_nh = bhh[j + 2 * H_DIM];

    const int  crow = (w << 2) | lk;
    const int  gm   = m0 + crow;
    const long opos = (long)gm * H_DIM + j;

    float hprev = f_init ? f_init[opos] : 0.0f;

    constexpr int NKX = (WXK == 128) ? 1 : 8;
    short8v xcur[NKX];
    {
        const bf16* xr = xbase + (long)(m0 + ln) * WXK + wkox + lk * 8;
#pragma unroll
        for (int ks = 0; ks < NKX; ++ks) xcur[ks] = ldg8(xr + ks * 32);
    }

    for (int t = 0; t < nsteps; ++t) {
        f32x4 aR{0,0,0,0}, aZ{0,0,0,0}, aNI{0,0,0,0}, aNH{0,0,0,0};

        if constexpr (WXK == 128) {
            int o = WH_BYTES + ln * 256 + ((wkox + lk * 8) << 1);
            short8v br  = *(const short8v*)(smem + ((o       ) ^ swz));
            short8v bz  = *(const short8v*)(smem + ((o + 4096) ^ swz));
            short8v bnn = *(const short8v*)(smem + ((o + 8192) ^ swz));
            aR  = MFMA16(xcur[0], br,  aR);
            aZ  = MFMA16(xcur[0], bz,  aZ);
            aNI = MFMA16(xcur[0], bnn, aNI);
        } else {
            const bf16* wxr = WxG + (long)(j0 + ln) * 1024 + wkox + lk * 8;
#pragma unroll
            for (int ks = 0; ks < 8; ++ks) {
                short8v br  = ldg8(wxr + ks * 32);
                short8v bz  = ldg8(wxr + (1 << 20) + ks * 32);
                short8v bnn = ldg8(wxr + (2 << 20) + ks * 32);
                aR  = MFMA16(xcur[ks], br,  aR);
                aZ  = MFMA16(xcur[ks], bz,  aZ);
                aNI = MFMA16(xcur[ks], bnn, aNI);
            }
        }

        const bf16* bf_in = SEQ ? hin + (long)t * HB : hin + (long)(t & 1) * HB;
        const bf16* ha = bf_in + (long)(m0 + ln) * H_DIM + wkoh + lk * 8;
        short8v ah[8];
#pragma unroll
        for (int ks = 0; ks < 8; ++ks)
            ah[ks] = SEQ ? ldg8(ha + ks * 32) : ld_byp16(ha + ks * 32);

#pragma unroll
        for (int ks = 0; ks < 8; ++ks) {
            int o = whb0 + ks * 64;
            short8v br  = *(const short8v*)(smem + ((o        ) ^ swz));
            short8v bz  = *(const short8v*)(smem + ((o + 32768) ^ swz));
            short8v bnn = *(const short8v*)(smem + ((o + 65536) ^ swz));
            aR  = MFMA16(ah[ks], br,  aR);
            aZ  = MFMA16(ah[ks], bz,  aZ);
            aNH = MFMA16(ah[ks], bnn, aNH);
        }

        float* red = sm_red + (t & 1) * 4608;
#pragma unroll
        for (int a = 0; a < 4; ++a) {
            f32x4 v = (a == 0) ? aR : (a == 1) ? aZ : (a == 2) ? aNI : aNH;
            int base = ((w << 2) + a) * 288 + (lk * 4) * 18 + ln;
#pragma unroll
            for (int e = 0; e < 4; ++e)
                red[base + e * 18] = v[e];
        }
        __syncthreads();

        float sR = 0, sZ = 0, sNI = 0, sNH = 0;
#pragma unroll
        for (int w2 = 0; w2 < 4; ++w2) {
            int tb = (w2 << 2) * 288 + crow * 18 + ln;
            sR  += red[tb];
            sZ  += red[tb + 288];
            sNI += red[tb + 576];
            sNH += red[tb + 864];
        }
        float rr = 1.0f / (1.0f + __expf(-(sR + bias_r)));
        float zz = 1.0f / (1.0f + __expf(-(sZ + bias_z)));
        float xn = (sNI + bias_ni) + rr * (sNH + bias_nh);
        float nn = 2.0f / (1.0f + __expf(-2.0f * xn)) - 1.0f;
        float hv = (1.0f - zz) * nn + zz * hprev;
        hprev = hv;

        {
            bf16* wr = SEQ ? hout + (long)t * HB
                           : const_cast<bf16*>(hin) + (long)((t + 1) & 1) * HB;
            float ho = __shfl_xor(hv, 1);
            if ((ln & 1) == 0) {
                unsigned pk = (unsigned)f2bf_bits(hv)
                            | ((unsigned)f2bf_bits(ho) << 16);
                st_coh((unsigned*)(wr + (opos & ~1L)), pk);
            }
        }
        if (t == nsteps - 1 && f_final) f_final[opos] = hv;
        (void)flags;
    }
}

// ---------------------------------------------------------------------------
__global__ __launch_bounds__(1024) void head_kernel(
    const float* __restrict__ h2,
    const float* __restrict__ fc_W, const float* __restrict__ fc_b,
    const float* __restrict__ out_W, const float* __restrict__ out_b,
    float* __restrict__ y)
{
    __shared__ float acc_s[FC_DIM][B_DIM];
    const int b = threadIdx.x & 63;
    const int f = threadIdx.x >> 6;
    const float* wp = fc_W + (long)f * H_DIM;
    const float* hp = h2 + (long)b * H_DIM;
    float a = fc_b[f];
#pragma unroll 8
    for (int k = 0; k < H_DIM; ++k)
        a = fmaf(hp[k], wp[k], a);
    a = fmaxf(a, 0.0f);
    acc_s[f][b] = a * out_W[f];
    __syncthreads();
    if (threadIdx.x < 64) {
        float s = out_b[0];
#pragma unroll
        for (int f2 = 0; f2 < FC_DIM; ++f2) s += acc_s[f2][b];
        y[b] = s;
    }
}

// ---------------------------------------------------------------------------
extern "C" void kernel_launch(void* const* d_in, const int* in_sizes, int n_in,
                              void* d_out, int out_size, void* d_ws, size_t ws_size,
                              hipStream_t stream)
{
    const float* x      = (const float*)d_in[0];
    const float* e_Wih0 = (const float*)d_in[1];
    const float* e_Whh0 = (const float*)d_in[2];
    const float* e_bih0 = (const float*)d_in[3];
    const float* e_bhh0 = (const float*)d_in[4];
    const float* e_Wih1 = (const float*)d_in[5];
    const float* e_Whh1 = (const float*)d_in[6];
    const float* e_bih1 = (const float*)d_in[7];
    const float* e_bhh1 = (const float*)d_in[8];
    const float* d_Wih0 = (const float*)d_in[9];
    const float* d_Whh0 = (const float*)d_in[10];
    const float* d_bih0 = (const float*)d_in[11];
    const float* d_bhh0 = (const float*)d_in[12];
    const float* d_Wih1 = (const float*)d_in[13];
    const float* d_Whh1 = (const float*)d_in[14];
    const float* d_bih1 = (const float*)d_in[15];
    const float* d_bhh1 = (const float*)d_in[16];
    const float* fc_W   = (const float*)d_in[17];
    const float* fc_b   = (const float*)d_in[18];
    const float* out_W  = (const float*)d_in[19];
    const float* out_b  = (const float*)d_in[20];
    (void)in_sizes; (void)n_in; (void)out_size; (void)ws_size;

    char* p = (char*)d_ws;
    auto alloc = [&](size_t bytes) -> char* {
        char* r = p; p += (bytes + 255) & ~(size_t)255; return r;
    };
    bf16*  x_bf  = (bf16*)alloc((size_t)T_DIM * B_DIM * I_PAD * 2);
    bf16*  wih0e = (bf16*)alloc(3072ull * 128 * 2);
    bf16*  whh0e = (bf16*)alloc(3072ull * 1024 * 2);
    bf16*  wih1e = (bf16*)alloc(3072ull * 1024 * 2);
    bf16*  whh1e = (bf16*)alloc(3072ull * 1024 * 2);
    bf16*  wih0d = (bf16*)alloc(3072ull * 128 * 2);
    bf16*  whh0d = (bf16*)alloc(3072ull * 1024 * 2);
    bf16*  wih1d = (bf16*)alloc(3072ull * 1024 * 2);
    bf16*  whh1d = (bf16*)alloc(3072ull * 1024 * 2);
    bf16*  h1all = (bf16*)alloc(514ull * HB * 2);   // slots 0..513
    bf16*  h2rg  = (bf16*)alloc(5ull * HB * 2);     // 4-slot ring + spare
    bf16*  hd1b  = (bf16*)alloc((size_t)HB * 2);
    float* hf1f  = (float*)alloc((size_t)HB * 4);
    float* hf2f  = (float*)alloc((size_t)HB * 4);
    float* hd1f  = (float*)alloc((size_t)HB * 4);
    float* hd2f  = (float*)alloc((size_t)HB * 4);
    unsigned* fl = (unsigned*)alloc(8192);          // 2 layers x 1024 dwords

    constexpr int RED = 2 * 4608 * 4;
    constexpr int S1  = 98304 + 12288 + RED;        // decoder cell 1
    constexpr int S2  = 98304 + RED;                // decoder cell 2
    (void)hipFuncSetAttribute((const void*)gru_pass<128, false, true>,
                              hipFuncAttributeMaxDynamicSharedMemorySize, S1);
    (void)hipFuncSetAttribute((const void*)gru_pass<1024, true, false>,
                              hipFuncAttributeMaxDynamicSharedMemorySize, S2);

    cvt_x_kernel<<<(T_DIM * B_DIM * I_PAD) / 256, 256, 0, stream>>>(x, x_bf);
    auto cvt = [&](const float* in, bf16* out, int kin, int kp) {
        long total = 3072L * kp;
        cvt_pad<<<(int)((total + 255) / 256), 256, 0, stream>>>(in, out, kin, kp, total);
    };
    cvt(e_Wih0, wih0e, 118, 128);
    cvt(e_Whh0, whh0e, 1024, 1024);
    cvt(e_Wih1, wih1e, 1024, 1024);
    cvt(e_Whh1, whh1e, 1024, 1024);
    cvt(d_Wih0, wih0d, 118, 128);
    cvt(d_Whh0, whh0d, 1024, 1024);
    cvt(d_Wih1, wih1d, 1024, 1024);
    cvt(d_Whh1, whh1d, 1024, 1024);

    // deterministic per-launch state
    hipMemsetAsync(h1all, 0, (size_t)HB * 2, stream);            // h1(-1) = 0
    hipMemsetAsync(h2rg + 3ull * HB, 0, (size_t)HB * 2, stream); // h2(-1) = 0 (slot 3)
    hipMemsetAsync(fl,    0, 8192, stream);

    // concurrent two-layer encoder: 512 blocks (0-255 L1, 256-511 L2), 2/CU
    gru_enc2<<<512, 256, 0, stream>>>(
        x_bf, wih0e, whh0e, wih1e, whh1e,
        e_bih0, e_bhh0, e_bih1, e_bhh1,
        h1all, h2rg, hf1f, hf2f, fl);
    // h1(511) -> h1all slot 512 (+ hf1f); h2(511) -> ring slot 511&3 = 3 (+ hf2f)

    // decoder cell 1: x = x[:,511,:], h = h1(511) (cached write-once slot)
    gru_pass<128, false, true><<<256, 256, S1, stream>>>(
        x_bf + 511L * B_DIM * I_PAD, 0, wih0d, whh0d, d_bih0, d_bhh0,
        h1all + 512L * HB, hd1b, hf1f, hd1f, 1, nullptr);

    // decoder cell 2: x = hd1, h = h2(511) (ring slot 3; bypass reads;
    // dummy bf16 out lands in ring slot 4 = spare)
    gru_pass<1024, true, false><<<256, 256, S2, stream>>>(
        hd1b, 0, wih1d, whh1d, d_bih1, d_bhh1,
        h2rg + 3L * HB, nullptr, hf2f, hd2f, 1, nullptr);

    head_kernel<<<1, 1024, 0, stream>>>(hd2f, fc_W, fc_b, out_W, out_b,
                                        (float*)d_out);
}